// Round 1
// baseline (147.882 us; speedup 1.0000x reference)
//
#include <hip/hip_runtime.h>

#define BATCH 16384
#define LATENT 128
#define HIDDEN 64
#define INDIM 100
#define KPAD 128
#define TANH_SCALE 2.885390081777927f   // 2*log2(e): exp(2x) = exp2(SCALE*x)

typedef short shortx8 __attribute__((ext_vector_type(8)));
typedef float floatx4 __attribute__((ext_vector_type(4)));

__device__ __forceinline__ short f2bf(float f) {
    union { float f; unsigned u; } v; v.f = f;
    unsigned r = v.u + 0x7FFF + ((v.u >> 16) & 1);   // RNE, inputs finite
    return (short)(r >> 16);
}

#if __has_builtin(__builtin_amdgcn_exp2f)
#define EXP2F(x) __builtin_amdgcn_exp2f(x)
#else
#define EXP2F(x) __exp2f(x)
#endif
#if __has_builtin(__builtin_amdgcn_rcpf)
#define RCPF(x) __builtin_amdgcn_rcpf(x)
#else
#define RCPF(x) (1.0f / (x))
#endif

#define N_U_CHUNKS (BATCH * KPAD / 8)            // 262144
#define N_W_CHUNKS (LATENT * HIDDEN * KPAD / 8)  // 131072

// --- fused pre-pass: bf16 fragment-major uf (ones col k=100) and wf
// (b1 at k=100). W1/b1 pre-scaled by 2*log2(e) so the MFMA output feeds
// exp2 directly (saves one v_mul per tanh). Final block computes
// b2eff[lat] = b2[lat] + sum_h W2[lat][h]  (tanh = 1 - 2/(e+1) algebra). ---
__global__ __launch_bounds__(256) void prep_all(const float* __restrict__ u,
                                                const float* __restrict__ W1,
                                                const float* __restrict__ b1,
                                                const float* __restrict__ W2,
                                                const float* __restrict__ b2,
                                                shortx8* __restrict__ uf,
                                                shortx8* __restrict__ wf,
                                                float* __restrict__ b2eff) {
    int c = blockIdx.x * 256 + threadIdx.x;
    if (c < N_U_CHUNKS) {
        int lane = c & 63;
        int kt = (c >> 6) & 3;
        int g = c >> 8;
        int row = g * 16 + (lane & 15);
        int kbase = kt * 32 + ((lane >> 4) << 3);
        shortx8 v;
        if (kbase + 7 < INDIM) {
            const float4* p = (const float4*)(u + row * INDIM + kbase);
            float4 f0 = p[0], f1 = p[1];
            v[0] = f2bf(f0.x); v[1] = f2bf(f0.y); v[2] = f2bf(f0.z); v[3] = f2bf(f0.w);
            v[4] = f2bf(f1.x); v[5] = f2bf(f1.y); v[6] = f2bf(f1.z); v[7] = f2bf(f1.w);
        } else {
#pragma unroll
            for (int j = 0; j < 8; j++) {
                int k = kbase + j;
                float f = (k < INDIM) ? u[row * INDIM + k] : (k == INDIM ? 1.0f : 0.0f);
                v[j] = f2bf(f);
            }
        }
        uf[c] = v;
    } else if (c < N_U_CHUNKS + N_W_CHUNKS) {
        int c2 = c - N_U_CHUNKS;
        int lane = c2 & 63;
        int kt = (c2 >> 6) & 3;
        int nt = (c2 >> 8) & 3;
        int lat = c2 >> 10;
        int h = nt * 16 + (lane & 15);
        int hw = lat * HIDDEN + h;
        int kbase = kt * 32 + ((lane >> 4) << 3);
        shortx8 v;
        if (kbase + 7 < INDIM) {
            const float4* p = (const float4*)(W1 + hw * INDIM + kbase);
            float4 f0 = p[0], f1 = p[1];
            v[0] = f2bf(f0.x * TANH_SCALE); v[1] = f2bf(f0.y * TANH_SCALE);
            v[2] = f2bf(f0.z * TANH_SCALE); v[3] = f2bf(f0.w * TANH_SCALE);
            v[4] = f2bf(f1.x * TANH_SCALE); v[5] = f2bf(f1.y * TANH_SCALE);
            v[6] = f2bf(f1.z * TANH_SCALE); v[7] = f2bf(f1.w * TANH_SCALE);
        } else {
#pragma unroll
            for (int j = 0; j < 8; j++) {
                int k = kbase + j;
                float f = (k < INDIM) ? W1[hw * INDIM + k] * TANH_SCALE
                                      : (k == INDIM ? b1[hw] * TANH_SCALE : 0.0f);
                v[j] = f2bf(f);
            }
        }
        wf[c2] = v;
    } else {
        int lat = c - (N_U_CHUNKS + N_W_CHUNKS);
        if (lat < LATENT) {
            float s = b2[lat];
            const float* wp = W2 + lat * HIDDEN;
#pragma unroll 8
            for (int h = 0; h < HIDDEN; h++) s += wp[h];
            b2eff[lat] = s;
        }
    }
}

// ---------------------------------------------------------------------------
// h-split main kernel. Block = 4 waves, ALL the same latent, each wave owns
// ONE nt-tile (16 h-values): afr[4] = 16 VGPRs (vs 64 for the full latent in
// the previous version, whose real unified VGPR+AGPR allocation was ~160 ->
// 3 waves/SIMD, Occupancy 34%). Target ~70-80 regs -> 6 waves/SIMD.
// Each wave: 8 batch-groups of 16 rows; per group 4 ub loads + 4 MFMAs +
// 16-element tanh epilogue + quad shfl reduce; per-group scalar banked in
// s_arr[8]. ONE __syncthreads at the end; waves exchange partials via 2KB
// LDS and each wave stores 2 groups.
// Orientation (proven round 5): mfma(afr, ub) -> D row = h (nt*16+q*4+r),
// col = batch (lane&15). s = sum_h -2*w2[h]/(exp2(y)+1); b2eff carries
// b2 + sum_h w2.
// grid: 16384 blocks x 256 thr; lat = bx>>7, G0 = (bx&127)*8 row-groups.
// Blocks sharing a uf window have bx stride 128 == 0 mod 8 -> same XCD L2.
// ---------------------------------------------------------------------------
__global__ __launch_bounds__(256, 6) void branch_mlp(const shortx8* __restrict__ uf,
                                                     const shortx8* __restrict__ wf,
                                                     const float* __restrict__ W2,
                                                     const float* __restrict__ b2eff,
                                                     float* __restrict__ out) {
    int tid = threadIdx.x;
    int lane = tid & 63;
    int w = tid >> 6;            // nt-tile owned by this wave
    int bx = blockIdx.x;
    int lat = bx >> 7;
    int G0 = (bx & 127) * 8;     // first of 8 batch 16-row groups
    int q = lane >> 4;

    __shared__ float red[4][128];   // [wave][g*16 + batchcol]

    // this wave's 4 weight fragment chunks (16 VGPRs)
    shortx8 afr[4];
    const shortx8* wb = wf + (size_t)lat * 16 * 64 + (size_t)w * 4 * 64 + lane;
#pragma unroll
    for (int kt = 0; kt < 4; kt++)
        afr[kt] = wb[kt * 64];

    // -2*W2 for this lane's 4 h-values (h = w*16 + q*4 + r)
    float4 t = *(const float4*)(W2 + lat * HIDDEN + w * 16 + q * 4);
    float4 w2v = make_float4(-2.0f * t.x, -2.0f * t.y, -2.0f * t.z, -2.0f * t.w);
    float b2v = b2eff[lat];

    const shortx8* ua = uf + (size_t)G0 * 4 * 64 + lane;
    float s_arr[8];

#pragma unroll
    for (int g = 0; g < 8; g++) {
        shortx8 ub[4];
#pragma unroll
        for (int kt = 0; kt < 4; kt++)
            ub[kt] = ua[(g * 4 + kt) * 64];

        floatx4 acc = {};   // rows h (this nt), cols batch
#pragma unroll
        for (int kt = 0; kt < 4; kt++)
            acc = __builtin_amdgcn_mfma_f32_16x16x32_bf16(afr[kt], ub[kt], acc, 0, 0, 0);

        float s = 0.0f;
#pragma unroll
        for (int r = 0; r < 4; r++) {
            float e = EXP2F(acc[r]);          // = exp(2x), scale folded into W1
            float rr = RCPF(e + 1.0f);
            s = fmaf((&w2v.x)[r], rr, s);     // s += -2*w2*rr
        }
        s += __shfl_xor(s, 16, 64);
        s += __shfl_xor(s, 32, 64);           // sum over the 4 lane-quadrants
        s_arr[g] = s;                         // partial over this wave's 16 h
    }

    // cross-wave reduction: each wave banks its 8x16 partials, one barrier,
    // then wave w finalizes groups 2w and 2w+1.
    if (lane < 16) {
#pragma unroll
        for (int g = 0; g < 8; g++)
            red[w][g * 16 + lane] = s_arr[g];
    }
    __syncthreads();

    if (lane < 16) {
        float* outp = out + (size_t)G0 * 16 * LATENT + lat;
#pragma unroll
        for (int j = 0; j < 2; j++) {
            int g = w * 2 + j;
            float s = red[0][g * 16 + lane] + red[1][g * 16 + lane] +
                      red[2][g * 16 + lane] + red[3][g * 16 + lane] + b2v;
            outp[(g * 16 + lane) * LATENT] = s;
        }
    }
}

// --- fp32 fallback (no workspace needed) ---
__global__ __launch_bounds__(256) void fallback_kernel(const float* __restrict__ u, const float* __restrict__ W1,
                                                       const float* __restrict__ b1, const float* __restrict__ W2,
                                                       const float* __restrict__ b2, float* __restrict__ out) {
    int idx = blockIdx.x * 256 + threadIdx.x;
    if (idx >= BATCH * LATENT) return;
    int b = idx >> 7;
    int lat = idx & 127;
    const float* ub = u + b * INDIM;
    float s = 0.0f;
    for (int h = 0; h < HIDDEN; h++) {
        const float* wp = W1 + (lat * HIDDEN + h) * INDIM;
        float dd = b1[lat * HIDDEN + h];
        for (int k = 0; k < INDIM; k++) dd += ub[k] * wp[k];
        s += tanhf(dd) * W2[lat * HIDDEN + h];
    }
    out[idx] = s + b2[lat];
}

extern "C" void kernel_launch(void* const* d_in, const int* in_sizes, int n_in,
                              void* d_out, int out_size, void* d_ws, size_t ws_size,
                              hipStream_t stream) {
    const float* u  = (const float*)d_in[0];
    const float* W1 = (const float*)d_in[1];
    const float* b1 = (const float*)d_in[2];
    const float* W2 = (const float*)d_in[3];
    const float* b2 = (const float*)d_in[4];
    float* out = (float*)d_out;

    const size_t UF_BYTES = (size_t)BATCH * KPAD * 2;           // 4 MiB
    const size_t WF_BYTES = (size_t)LATENT * HIDDEN * KPAD * 2; // 2 MiB
    const size_t B2_BYTES = LATENT * sizeof(float);

    if (ws_size < UF_BYTES + WF_BYTES + B2_BYTES) {
        fallback_kernel<<<(BATCH * LATENT + 255) / 256, 256, 0, stream>>>(u, W1, b1, W2, b2, out);
        return;
    }

    shortx8* uf = (shortx8*)d_ws;
    shortx8* wf = (shortx8*)((char*)d_ws + UF_BYTES);
    float* b2eff = (float*)((char*)d_ws + UF_BYTES + WF_BYTES);

    // 1536 blocks cover uf+wf chunks; +1 block computes b2eff
    prep_all<<<(N_U_CHUNKS + N_W_CHUNKS) / 256 + 1, 256, 0, stream>>>(u, W1, b1, W2, b2, uf, wf, b2eff);
    branch_mlp<<<16384, 256, 0, stream>>>(uf, wf, W2, b2eff, out);
}

// Round 2
// 112.512 us; speedup vs baseline: 1.3144x; 1.3144x over previous
//
#include <hip/hip_runtime.h>

#define BATCH 16384
#define LATENT 128
#define HIDDEN 64
#define INDIM 100
#define KPAD 128
#define TANH_SCALE 2.885390081777927f   // 2*log2(e): exp(2x) = exp2(SCALE*x)

typedef short shortx8 __attribute__((ext_vector_type(8)));
typedef float floatx4 __attribute__((ext_vector_type(4)));

__device__ __forceinline__ short f2bf(float f) {
    union { float f; unsigned u; } v; v.f = f;
    unsigned r = v.u + 0x7FFF + ((v.u >> 16) & 1);   // RNE, inputs finite
    return (short)(r >> 16);
}

#if __has_builtin(__builtin_amdgcn_exp2f)
#define EXP2F(x) __builtin_amdgcn_exp2f(x)
#else
#define EXP2F(x) __exp2f(x)
#endif
#if __has_builtin(__builtin_amdgcn_rcpf)
#define RCPF(x) __builtin_amdgcn_rcpf(x)
#else
#define RCPF(x) (1.0f / (x))
#endif

#define N_U_CHUNKS (BATCH * KPAD / 8)            // 262144
#define N_W_CHUNKS (LATENT * HIDDEN * KPAD / 8)  // 131072

// --- fused pre-pass: bf16 fragment-major uf (ones col k=100) and wf
// (b1 at k=100). W1/b1 pre-scaled by 2*log2(e) so the MFMA output feeds
// exp2 directly (saves one v_mul per tanh). Final block computes
// b2eff[lat] = b2[lat] + sum_h W2[lat][h]  (tanh = 1 - 2/(e+1) algebra). ---
__global__ __launch_bounds__(256) void prep_all(const float* __restrict__ u,
                                                const float* __restrict__ W1,
                                                const float* __restrict__ b1,
                                                const float* __restrict__ W2,
                                                const float* __restrict__ b2,
                                                shortx8* __restrict__ uf,
                                                shortx8* __restrict__ wf,
                                                float* __restrict__ b2eff) {
    int c = blockIdx.x * 256 + threadIdx.x;
    if (c < N_U_CHUNKS) {
        int lane = c & 63;
        int kt = (c >> 6) & 3;
        int g = c >> 8;
        int row = g * 16 + (lane & 15);
        int kbase = kt * 32 + ((lane >> 4) << 3);
        shortx8 v;
        if (kbase + 7 < INDIM) {
            const float4* p = (const float4*)(u + row * INDIM + kbase);
            float4 f0 = p[0], f1 = p[1];
            v[0] = f2bf(f0.x); v[1] = f2bf(f0.y); v[2] = f2bf(f0.z); v[3] = f2bf(f0.w);
            v[4] = f2bf(f1.x); v[5] = f2bf(f1.y); v[6] = f2bf(f1.z); v[7] = f2bf(f1.w);
        } else {
#pragma unroll
            for (int j = 0; j < 8; j++) {
                int k = kbase + j;
                float f = (k < INDIM) ? u[row * INDIM + k] : (k == INDIM ? 1.0f : 0.0f);
                v[j] = f2bf(f);
            }
        }
        uf[c] = v;
    } else if (c < N_U_CHUNKS + N_W_CHUNKS) {
        int c2 = c - N_U_CHUNKS;
        int lane = c2 & 63;
        int kt = (c2 >> 6) & 3;
        int nt = (c2 >> 8) & 3;
        int lat = c2 >> 10;
        int h = nt * 16 + (lane & 15);
        int hw = lat * HIDDEN + h;
        int kbase = kt * 32 + ((lane >> 4) << 3);
        shortx8 v;
        if (kbase + 7 < INDIM) {
            const float4* p = (const float4*)(W1 + hw * INDIM + kbase);
            float4 f0 = p[0], f1 = p[1];
            v[0] = f2bf(f0.x * TANH_SCALE); v[1] = f2bf(f0.y * TANH_SCALE);
            v[2] = f2bf(f0.z * TANH_SCALE); v[3] = f2bf(f0.w * TANH_SCALE);
            v[4] = f2bf(f1.x * TANH_SCALE); v[5] = f2bf(f1.y * TANH_SCALE);
            v[6] = f2bf(f1.z * TANH_SCALE); v[7] = f2bf(f1.w * TANH_SCALE);
        } else {
#pragma unroll
            for (int j = 0; j < 8; j++) {
                int k = kbase + j;
                float f = (k < INDIM) ? W1[hw * INDIM + k] * TANH_SCALE
                                      : (k == INDIM ? b1[hw] * TANH_SCALE : 0.0f);
                v[j] = f2bf(f);
            }
        }
        wf[c2] = v;
    } else {
        int lat = c - (N_U_CHUNKS + N_W_CHUNKS);
        if (lat < LATENT) {
            float s = b2[lat];
            const float* wp = W2 + lat * HIDDEN;
#pragma unroll 8
            for (int h = 0; h < HIDDEN; h++) s += wp[h];
            b2eff[lat] = s;
        }
    }
}

// ---------------------------------------------------------------------------
// Weight-stationary main kernel (round-0 structure: wave = ONE latent,
// afr[4][4] loaded once, 8 batch-groups of 16 rows stream through).
// Round-2 changes:
//  (1) pairwise rcp combining in the tanh epilogue: wa/(ea+1)+wb/(eb+1)
//      = (wa*pb + wb*pa)/(pa*pb) -> 2 rcp/group-of-4 instead of 4 (exact
//      algebra, no approximation). Cuts epilogue issue cycles ~18%.
//  (2) -2*W2 lives in LDS (2 copies, indexed by g&1 so the reads are not
//      loop-invariant-hoisted back into 16 VGPRs) + amdgpu_waves_per_eu(4)
//      hard-caps the unified VGPR+AGPR budget at 128 -> 4 waves/SIMD
//      (round 0 allocated ~140 -> only 2.75 waves/SIMD, VALUBusy 52%).
// Orientation (proven): mfma(afr, ub) -> D row = h (nt*16+q*4+r),
// col = batch (lane&15). b2eff carries b2 + sum_h w2.
// grid: 4096 blocks x 256 thr; block = 4 waves of the SAME latent (L1 reuse
// of the 16KB wf panel).
// ---------------------------------------------------------------------------
__global__ __launch_bounds__(256) __attribute__((amdgpu_waves_per_eu(4, 8)))
void branch_mlp(const shortx8* __restrict__ uf,
                const shortx8* __restrict__ wf,
                const float* __restrict__ W2,
                const float* __restrict__ b2eff,
                float* __restrict__ out) {
    int tid = threadIdx.x;
    int lane = tid & 63;
    int w = tid >> 6;
    int bx = blockIdx.x;
    int lat = bx >> 5;
    int G0 = (bx & 31) * 32 + w * 8;          // first of 8 batch 16-row groups
    int q = lane >> 4;

    // -2*W2 for this latent, two identical copies (defeats LIC hoisting of
    // the per-group reads into long-lived registers).
    __shared__ float w2s[2][HIDDEN];
    if (tid < 128) w2s[tid >> 6][tid & 63] = -2.0f * W2[lat * HIDDEN + (tid & 63)];
    __syncthreads();

    // latent-resident weights: 16 fragment chunks (64 regs)
    shortx8 afr[4][4];
    const shortx8* wb = wf + (size_t)lat * 16 * 64 + lane;
#pragma unroll
    for (int nt = 0; nt < 4; nt++)
#pragma unroll
        for (int kt = 0; kt < 4; kt++)
            afr[nt][kt] = wb[(nt * 4 + kt) * 64];

    float b2v = b2eff[lat];

    const shortx8* ua = uf + (size_t)G0 * 4 * 64 + lane;
    float* outp = out + (size_t)G0 * 16 * LATENT + lat;

#pragma unroll
    for (int g = 0; g < 8; g++) {
        shortx8 ub[4];
#pragma unroll
        for (int kt = 0; kt < 4; kt++)
            ub[kt] = ua[(g * 4 + kt) * 64];

        floatx4 acc[4] = {};   // [nt]: rows h, cols batch
#pragma unroll
        for (int kt = 0; kt < 4; kt++)
#pragma unroll
            for (int nt = 0; nt < 4; nt++)
                acc[nt] = __builtin_amdgcn_mfma_f32_16x16x32_bf16(afr[nt][kt], ub[kt], acc[nt], 0, 0, 0);

        float s = 0.0f;
#pragma unroll
        for (int nt = 0; nt < 4; nt++) {
            float4 wv = *(const float4*)(&w2s[g & 1][nt * 16 + q * 4]);
            float e0 = EXP2F(acc[nt][0]);     // = exp(2x), scale folded into W1
            float e1 = EXP2F(acc[nt][1]);
            float e2 = EXP2F(acc[nt][2]);
            float e3 = EXP2F(acc[nt][3]);
            float p0 = e0 + 1.0f, p1 = e1 + 1.0f;
            float p2 = e2 + 1.0f, p3 = e3 + 1.0f;
            float n01 = fmaf(wv.x, p1, wv.y * p0);   // (wa*pb + wb*pa)
            float n23 = fmaf(wv.z, p3, wv.w * p2);
            s = fmaf(n01, RCPF(p0 * p1), s);         // += num/(pa*pb)
            s = fmaf(n23, RCPF(p2 * p3), s);
        }
        s += __shfl_xor(s, 16, 64);
        s += __shfl_xor(s, 32, 64);
        if (lane < 16)
            outp[(g * 16 + lane) * LATENT] = s + b2v; // + b2 + sum_h w2
    }
}

// --- fp32 fallback (no workspace needed) ---
__global__ __launch_bounds__(256) void fallback_kernel(const float* __restrict__ u, const float* __restrict__ W1,
                                                       const float* __restrict__ b1, const float* __restrict__ W2,
                                                       const float* __restrict__ b2, float* __restrict__ out) {
    int idx = blockIdx.x * 256 + threadIdx.x;
    if (idx >= BATCH * LATENT) return;
    int b = idx >> 7;
    int lat = idx & 127;
    const float* ub = u + b * INDIM;
    float s = 0.0f;
    for (int h = 0; h < HIDDEN; h++) {
        const float* wp = W1 + (lat * HIDDEN + h) * INDIM;
        float dd = b1[lat * HIDDEN + h];
        for (int k = 0; k < INDIM; k++) dd += ub[k] * wp[k];
        s += tanhf(dd) * W2[lat * HIDDEN + h];
    }
    out[idx] = s + b2[lat];
}

extern "C" void kernel_launch(void* const* d_in, const int* in_sizes, int n_in,
                              void* d_out, int out_size, void* d_ws, size_t ws_size,
                              hipStream_t stream) {
    const float* u  = (const float*)d_in[0];
    const float* W1 = (const float*)d_in[1];
    const float* b1 = (const float*)d_in[2];
    const float* W2 = (const float*)d_in[3];
    const float* b2 = (const float*)d_in[4];
    float* out = (float*)d_out;

    const size_t UF_BYTES = (size_t)BATCH * KPAD * 2;           // 4 MiB
    const size_t WF_BYTES = (size_t)LATENT * HIDDEN * KPAD * 2; // 2 MiB
    const size_t B2_BYTES = LATENT * sizeof(float);

    if (ws_size < UF_BYTES + WF_BYTES + B2_BYTES) {
        fallback_kernel<<<(BATCH * LATENT + 255) / 256, 256, 0, stream>>>(u, W1, b1, W2, b2, out);
        return;
    }

    shortx8* uf = (shortx8*)d_ws;
    shortx8* wf = (shortx8*)((char*)d_ws + UF_BYTES);
    float* b2eff = (float*)((char*)d_ws + UF_BYTES + WF_BYTES);

    // 1536 blocks cover uf+wf chunks; +1 block computes b2eff
    prep_all<<<(N_U_CHUNKS + N_W_CHUNKS) / 256 + 1, 256, 0, stream>>>(u, W1, b1, W2, b2, uf, wf, b2eff);
    branch_mlp<<<4096, 256, 0, stream>>>(uf, wf, W2, b2eff, out);
}